// Round 1
// baseline (979.002 us; speedup 1.0000x reference)
//
#include <hip/hip_runtime.h>

#define NN 100000
#define NE 1000000
#define HD 64

// ---------------- degree / normalization ----------------

__global__ void k_init_deg(float* __restrict__ deg) {
    int i = blockIdx.x * blockDim.x + threadIdx.x;
    if (i < NN) deg[i] = 1.0f;   // self-loop contributes 1 to every node's degree
}

__global__ void k_accum_deg(const int* __restrict__ dst, float* __restrict__ deg) {
    int e = blockIdx.x * blockDim.x + threadIdx.x;
    if (e < NE) atomicAdd(&deg[dst[e]], 1.0f);
}

__global__ void k_dis(float* __restrict__ deg) {
    int i = blockIdx.x * blockDim.x + threadIdx.x;
    if (i < NN) deg[i] = rsqrtf(deg[i]);   // deg >= 1 always; in place: deg -> dis
}

// ---------------- layer pieces ----------------

// x [N,2] @ W1 [2,64] -> out [N,64]
__global__ void k_xform1(const float* __restrict__ x, const float* __restrict__ W1,
                         float* __restrict__ out) {
    int t = blockIdx.x * blockDim.x + threadIdx.x;
    if (t >= NN * HD) return;
    int i = t >> 6, j = t & 63;
    out[t] = x[2 * i] * W1[j] + x[2 * i + 1] * W1[HD + j];
}

// in [N,64] @ W [64,64] -> out [N,64]; one wave per row, W in LDS
__global__ __launch_bounds__(256) void k_xform64(const float* __restrict__ in,
                                                 const float* __restrict__ W,
                                                 float* __restrict__ out) {
    __shared__ float Ws[HD * HD];
    int tid = threadIdx.x;
#pragma unroll
    for (int k = 0; k < (HD * HD) / 256; ++k) Ws[k * 256 + tid] = W[k * 256 + tid];
    __syncthreads();

    int wave = tid >> 6, lane = tid & 63;
    int r = blockIdx.x * 4 + wave;
    if (r >= NN) return;

    float v = in[r * HD + lane];   // lane k holds in[r][k]
    float acc = 0.0f;
#pragma unroll
    for (int k = 0; k < HD; ++k)
        acc += __shfl(v, k) * Ws[k * HD + lane];   // 2-way LDS bank alias: free
    out[r * HD + lane] = acc;
}

// a[i][:] = h[i][:] * dis[i]^2   (self-loop term; also initializes accumulator)
__global__ void k_selfloop(const float* __restrict__ h, const float* __restrict__ dis,
                           float* __restrict__ a) {
    int t = blockIdx.x * blockDim.x + threadIdx.x;
    if (t >= NN * HD) return;
    int i = t >> 6;
    float d = dis[i];
    a[t] = h[t] * d * d;
}

// a[dst][:] += h[src][:] * dis[src]*dis[dst], one wave per edge
__global__ void k_scatter(const int* __restrict__ ei, const float* __restrict__ h,
                          const float* __restrict__ dis, float* __restrict__ a) {
    unsigned t = blockIdx.x * blockDim.x + threadIdx.x;   // < 64M, fits in 32b
    int e = (int)(t >> 6), j = (int)(t & 63);
    if (e >= NE) return;
    int s = ei[e];          // src
    int d = ei[NE + e];     // dst
    float w = dis[s] * dis[d];
    atomicAdd(&a[d * HD + j], h[s * HD + j] * w);
}

__global__ void k_bias_relu(float* __restrict__ a, const float* __restrict__ b) {
    int t = blockIdx.x * blockDim.x + threadIdx.x;
    if (t >= NN * HD) return;
    a[t] = fmaxf(a[t] + b[t & 63], 0.0f);
}

// out[i] = sum_j h[i][j]*Wl[j] + bl ; one wave per node
__global__ __launch_bounds__(256) void k_final(const float* __restrict__ h,
                                               const float* __restrict__ Wl,
                                               const float* __restrict__ bl,
                                               float* __restrict__ out) {
    int tid = threadIdx.x;
    int wave = tid >> 6, lane = tid & 63;
    int i = blockIdx.x * 4 + wave;
    if (i >= NN) return;
    float v = h[i * HD + lane] * Wl[lane];
#pragma unroll
    for (int off = 32; off > 0; off >>= 1) v += __shfl_xor(v, off);
    if (lane == 0) out[i] = v + bl[0];
}

// ---------------- launch ----------------

extern "C" void kernel_launch(void* const* d_in, const int* in_sizes, int n_in,
                              void* d_out, int out_size, void* d_ws, size_t ws_size,
                              hipStream_t stream) {
    const float* x  = (const float*)d_in[0];
    const int*   ei = (const int*)d_in[1];   // [2, E]: src = ei[0:E], dst = ei[E:2E]
    const float* W1 = (const float*)d_in[2];
    const float* b1 = (const float*)d_in[3];
    const float* W2 = (const float*)d_in[4];
    const float* b2 = (const float*)d_in[5];
    const float* W3 = (const float*)d_in[6];
    const float* b3 = (const float*)d_in[7];
    const float* Wl = (const float*)d_in[8];
    const float* bl = (const float*)d_in[9];

    float* dis = (float*)d_ws;           // NN floats (deg -> dis in place)
    float* hA  = dis + NN;               // NN*HD
    float* hB  = hA + (size_t)NN * HD;   // NN*HD

    const int B = 256;
    const int gN   = (NN + B - 1) / B;
    const int gE   = (NE + B - 1) / B;
    const int gNH  = (NN * HD + B - 1) / B;
    const int gEH  = (NE / 4);           // NE*HD/256 = 250000
    const int gRow = (NN + 3) / 4;       // 4 rows (waves) per block

    // normalization
    k_init_deg<<<gN, B, 0, stream>>>(dis);
    k_accum_deg<<<gE, B, 0, stream>>>(ei + NE, dis);
    k_dis<<<gN, B, 0, stream>>>(dis);

    // layer 1: x@W1 -> hA ; aggregate -> hB ; +b1, relu
    k_xform1<<<gNH, B, 0, stream>>>(x, W1, hA);
    k_selfloop<<<gNH, B, 0, stream>>>(hA, dis, hB);
    k_scatter<<<gEH, B, 0, stream>>>(ei, hA, dis, hB);
    k_bias_relu<<<gNH, B, 0, stream>>>(hB, b1);

    // layer 2
    k_xform64<<<gRow, B, 0, stream>>>(hB, W2, hA);
    k_selfloop<<<gNH, B, 0, stream>>>(hA, dis, hB);
    k_scatter<<<gEH, B, 0, stream>>>(ei, hA, dis, hB);
    k_bias_relu<<<gNH, B, 0, stream>>>(hB, b2);

    // layer 3
    k_xform64<<<gRow, B, 0, stream>>>(hB, W3, hA);
    k_selfloop<<<gNH, B, 0, stream>>>(hA, dis, hB);
    k_scatter<<<gEH, B, 0, stream>>>(ei, hA, dis, hB);
    k_bias_relu<<<gNH, B, 0, stream>>>(hB, b3);

    // final linear
    k_final<<<gRow, B, 0, stream>>>(hB, Wl, bl, (float*)d_out);
}

// Round 2
// 466.182 us; speedup vs baseline: 2.1000x; 2.1000x over previous
//
#include <hip/hip_runtime.h>

#define NN 100000
#define NE 1000000
#define HD 64

// ---------------- degree / normalization / CSR build ----------------

__global__ void k_init(int* __restrict__ cnt) {
    int i = blockIdx.x * blockDim.x + threadIdx.x;
    if (i < NN) cnt[i] = 1;   // self-loop
}

__global__ void k_count(const int* __restrict__ dst, int* __restrict__ cnt) {
    int e = blockIdx.x * blockDim.x + threadIdx.x;
    if (e < NE) atomicAdd(&cnt[dst[e]], 1);
}

// single-block exclusive scan of cnt[NN] -> rowptr[NN+1]
__global__ __launch_bounds__(1024) void k_scan(const int* __restrict__ cnt,
                                               int* __restrict__ rowptr) {
    __shared__ int wsum[16];
    __shared__ int carry;
    const int tid = threadIdx.x;
    const int lane = tid & 63, w = tid >> 6;
    if (tid == 0) carry = 0;
    __syncthreads();
    for (int base = 0; base < NN; base += 1024) {
        int i = base + tid;
        int v = (i < NN) ? cnt[i] : 0;
        int s = v;
#pragma unroll
        for (int off = 1; off < 64; off <<= 1) {
            int t = __shfl_up(s, off);
            if (lane >= off) s += t;
        }
        if (lane == 63) wsum[w] = s;
        __syncthreads();
        if (tid < 16) {
            int ws = wsum[tid];
#pragma unroll
            for (int off = 1; off < 16; off <<= 1) {
                int t = __shfl_up(ws, off);
                if (tid >= off) ws += t;
            }
            wsum[tid] = ws;
        }
        __syncthreads();
        int prev = carry + (w ? wsum[w - 1] : 0);
        if (i < NN) rowptr[i] = prev + s - v;   // exclusive
        int total = wsum[15];
        __syncthreads();
        if (tid == 0) carry += total;
        __syncthreads();
    }
    if (tid == 0) rowptr[NN] = carry;
}

__global__ void k_dis(const int* __restrict__ cnt, float* __restrict__ dis) {
    int i = blockIdx.x * blockDim.x + threadIdx.x;
    if (i < NN) dis[i] = rsqrtf((float)cnt[i]);   // cnt >= 1 always
}

// self-loop CSR entry, fill counter init (reuses cnt), pre-scaled x
__global__ void k_prep(int* __restrict__ fill, const int* __restrict__ rowptr,
                       int* __restrict__ col, const float2* __restrict__ x2,
                       const float* __restrict__ dis, float2* __restrict__ xs) {
    int i = blockIdx.x * blockDim.x + threadIdx.x;
    if (i >= NN) return;
    fill[i] = 1;
    col[rowptr[i]] = i;
    float d = dis[i];
    float2 xv = x2[i];
    xs[i] = make_float2(xv.x * d, xv.y * d);
}

__global__ void k_fill(const int* __restrict__ ei, const int* __restrict__ rowptr,
                       int* __restrict__ fill, int* __restrict__ col) {
    int e = blockIdx.x * blockDim.x + threadIdx.x;
    if (e >= NE) return;
    int d = ei[NE + e];
    int pos = rowptr[d] + atomicAdd(&fill[d], 1);
    col[pos] = ei[e];
}

// ---------------- fused layers ----------------
// invariant: input rows are pre-scaled by dis[src]; out_agg = dis[d] * sum(rows)
// non-last layers write relu(agg@W + b) * dis[node] (pre-scale for next layer)

// layer 1: aggregate xs [N,2], transform by W1 [2,64], write h*dis
__global__ __launch_bounds__(256) void k_layer1(const float2* __restrict__ xs,
        const int* __restrict__ rowptr, const int* __restrict__ col,
        const float* __restrict__ dis, const float* __restrict__ W1,
        const float* __restrict__ b1, float* __restrict__ hout) {
    int tid = threadIdx.x, lane = tid & 63, wv = tid >> 6;
    int node = blockIdx.x * 4 + wv;
    if (node >= NN) return;
    int start = rowptr[node], end = rowptr[node + 1];
    float ax = 0.f, ay = 0.f;
    for (int base = start; base < end; base += 64) {
        int idx = base + lane;
        bool ok = idx < end;
        int s = ok ? col[idx] : 0;          // clamp: pad/beyond entries unused
        float2 xv = xs[s];
        if (ok) { ax += xv.x; ay += xv.y; }
    }
#pragma unroll
    for (int off = 32; off; off >>= 1) {
        ax += __shfl_xor(ax, off);
        ay += __shfl_xor(ay, off);
    }
    float dd = dis[node];
    ax *= dd; ay *= dd;
    float o = fmaxf(ax * W1[lane] + ay * W1[HD + lane] + b1[lane], 0.f);
    hout[node * HD + lane] = o * dd;
}

// layers 2/3: aggregate 64-wide rows, transform by W [64,64] held in VGPRs.
// LAST fuses the final @Wl + bl dot and writes out[node] (1 float).
template <bool LAST>
__global__ __launch_bounds__(256) void k_layer(const float* __restrict__ hin,
        const int* __restrict__ rowptr, const int* __restrict__ col,
        const float* __restrict__ dis, const float* __restrict__ W,
        const float* __restrict__ b, const float* __restrict__ Wl,
        const float* __restrict__ bl, float* __restrict__ out) {
    int tid = threadIdx.x, lane = tid & 63, wv = tid >> 6;
    int node = blockIdx.x * 4 + wv;
    if (node >= NN) return;

    float Wr[HD];                       // column `lane` of W, in registers
#pragma unroll
    for (int k = 0; k < HD; ++k) Wr[k] = W[k * HD + lane];

    int start = rowptr[node], end = rowptr[node + 1];
    float agg = 0.f;
    for (int base = start; base < end; base += 64) {
        int colv = col[base + lane];    // coalesced; pad guarantees in-bounds read
        int m = min(64, end - base);
        for (int t = 0; t < m; ++t) {
            int s = __builtin_amdgcn_readlane(colv, t);   // uniform broadcast
            agg += hin[s * HD + lane];
        }
    }
    agg *= dis[node];

    float o = b[lane];
#pragma unroll
    for (int k = 0; k < HD; ++k) {
        float a = __int_as_float(__builtin_amdgcn_readlane(__float_as_int(agg), k));
        o = fmaf(a, Wr[k], o);
    }
    o = fmaxf(o, 0.f);

    if (!LAST) {
        out[node * HD + lane] = o * dis[node];
    } else {
        float v = o * Wl[lane];
#pragma unroll
        for (int off = 32; off; off >>= 1) v += __shfl_xor(v, off);
        if (lane == 0) out[node] = v + bl[0];
    }
}

// ---------------- launch ----------------

extern "C" void kernel_launch(void* const* d_in, const int* in_sizes, int n_in,
                              void* d_out, int out_size, void* d_ws, size_t ws_size,
                              hipStream_t stream) {
    const float* x  = (const float*)d_in[0];
    const int*   ei = (const int*)d_in[1];   // [2,E]: src = ei[0:E], dst = ei[E:2E]
    const float* W1 = (const float*)d_in[2];
    const float* b1 = (const float*)d_in[3];
    const float* W2 = (const float*)d_in[4];
    const float* b2 = (const float*)d_in[5];
    const float* W3 = (const float*)d_in[6];
    const float* b3 = (const float*)d_in[7];
    const float* Wl = (const float*)d_in[8];
    const float* bl = (const float*)d_in[9];

    // workspace layout (all 8B-aligned)
    int*    cnt    = (int*)d_ws;                    // NN ints (later reused as fill)
    float*  dis    = (float*)(cnt + NN);            // NN floats
    int*    rowptr = (int*)(dis + NN);              // NN+2 ints (pad for alignment)
    int*    col    = rowptr + (NN + 2);             // NN+NE+64 ints (64 = overread pad)
    float2* xs     = (float2*)(col + (NN + NE + 64)); // NN float2
    float*  hA     = (float*)(xs + NN);             // NN*HD
    float*  hB     = hA + (size_t)NN * HD;          // NN*HD

    const int B = 256;
    const int gN   = (NN + B - 1) / B;
    const int gE   = (NE + B - 1) / B;
    const int gRow = (NN + 3) / 4;      // one wave per node, 4 waves/block

    // CSR + normalization (rebuilt every call; deterministic up to fp sum order)
    k_init<<<gN, B, 0, stream>>>(cnt);
    k_count<<<gE, B, 0, stream>>>(ei + NE, cnt);
    k_scan<<<1, 1024, 0, stream>>>(cnt, rowptr);
    k_dis<<<gN, B, 0, stream>>>(cnt, dis);
    k_prep<<<gN, B, 0, stream>>>(cnt /*fill*/, rowptr, col, (const float2*)x, dis, xs);
    k_fill<<<gE, B, 0, stream>>>(ei, rowptr, cnt /*fill*/, col);

    // fused layers
    k_layer1<<<gRow, B, 0, stream>>>(xs, rowptr, col, dis, W1, b1, hA);
    k_layer<false><<<gRow, B, 0, stream>>>(hA, rowptr, col, dis, W2, b2, nullptr, nullptr, hB);
    k_layer<true ><<<gRow, B, 0, stream>>>(hB, rowptr, col, dis, W3, b3, Wl, bl, (float*)d_out);
}

// Round 3
// 281.579 us; speedup vs baseline: 3.4768x; 1.6556x over previous
//
#include <hip/hip_runtime.h>

#define NN 100000
#define NE 1000000
#define HD 64
#define SCAN_B 1024
#define NCHUNK ((NN + SCAN_B - 1) / SCAN_B)   // 98
#define DUMMY_OFF (NN * HD)                   // zeroed dummy row index*HD

// ---------------- degree / normalization / CSR build ----------------

__global__ void k_init(int* __restrict__ cnt) {
    int i = blockIdx.x * blockDim.x + threadIdx.x;
    if (i < NN) cnt[i] = 1;   // self-loop
}

__global__ void k_count(const int* __restrict__ dst, int* __restrict__ cnt) {
    int e = blockIdx.x * blockDim.x + threadIdx.x;
    if (e < NE) atomicAdd(&cnt[dst[e]], 1);
}

// phase 1: per-block exclusive scan; loc[i] = local exclusive, bsum[b] = block total
__global__ __launch_bounds__(1024) void k_scan1(const int* __restrict__ cnt,
                                                int* __restrict__ loc,
                                                int* __restrict__ bsum) {
    __shared__ int wsum[16];
    int tid = threadIdx.x;
    int lane = tid & 63, w = tid >> 6;
    int i = blockIdx.x * SCAN_B + tid;
    int v = (i < NN) ? cnt[i] : 0;
    int s = v;
#pragma unroll
    for (int off = 1; off < 64; off <<= 1) {
        int t = __shfl_up(s, off);
        if (lane >= off) s += t;
    }
    if (lane == 63) wsum[w] = s;
    __syncthreads();
    if (tid < 16) {
        int ws = wsum[tid];
#pragma unroll
        for (int off = 1; off < 16; off <<= 1) {
            int t = __shfl_up(ws, off);
            if (tid >= off) ws += t;
        }
        wsum[tid] = ws;
    }
    __syncthreads();
    int prev = w ? wsum[w - 1] : 0;
    if (i < NN) loc[i] = prev + s - v;
    if (tid == 1023) bsum[blockIdx.x] = prev + s;
}

// phase 2: one wave scans the NCHUNK block totals -> exclusive offsets
__global__ __launch_bounds__(64) void k_scan2(const int* __restrict__ bsum,
                                              int* __restrict__ boff) {
    int l = threadIdx.x;
    int a0 = (2 * l     < NCHUNK) ? bsum[2 * l]     : 0;
    int a1 = (2 * l + 1 < NCHUNK) ? bsum[2 * l + 1] : 0;
    int p = a0 + a1, s = p;
#pragma unroll
    for (int off = 1; off < 64; off <<= 1) {
        int t = __shfl_up(s, off);
        if (l >= off) s += t;
    }
    int ep = s - p;   // exclusive prefix of pair
    if (2 * l     < NCHUNK) boff[2 * l]     = ep;
    if (2 * l + 1 < NCHUNK) boff[2 * l + 1] = ep + a0;
}

__global__ void k_dis(const int* __restrict__ cnt, float* __restrict__ dis) {
    int i = blockIdx.x * blockDim.x + threadIdx.x;
    if (i < NN) dis[i] = rsqrtf((float)cnt[i]);   // cnt >= 1 always
}

// phase 3 fused: materialize rowptr, self-loop CSR entry, fill init,
// pre-scaled x, zero the dummy rows
__global__ void k_prep(const int* __restrict__ loc, const int* __restrict__ boff,
                       int* __restrict__ rowptr, int* __restrict__ fill,
                       int* __restrict__ col, const float2* __restrict__ x2,
                       const float* __restrict__ dis, float2* __restrict__ xs,
                       float* __restrict__ hA, float* __restrict__ hB) {
    int i = blockIdx.x * blockDim.x + threadIdx.x;
    if (i == 0) rowptr[NN] = NN + NE;                 // grand total is static
    if (i < HD) { hA[DUMMY_OFF + i] = 0.f; hB[DUMMY_OFF + i] = 0.f; }
    if (i >= NN) return;
    int r = loc[i] + boff[i >> 10];
    rowptr[i] = r;
    fill[i] = 1;
    col[r] = i;                                        // self-loop entry
    float d = dis[i];
    float2 xv = x2[i];
    xs[i] = make_float2(xv.x * d, xv.y * d);
}

__global__ void k_fill(const int* __restrict__ ei, const int* __restrict__ rowptr,
                       int* __restrict__ fill, int* __restrict__ col) {
    int e = blockIdx.x * blockDim.x + threadIdx.x;
    if (e >= NE) return;
    int d = ei[NE + e];
    int pos = rowptr[d] + atomicAdd(&fill[d], 1);
    col[pos] = ei[e];
}

// ---------------- fused layers ----------------
// invariant: input rows pre-scaled by dis[src]; agg = dis[d] * sum(rows);
// non-last layers write relu(agg@W + b) * dis[node] (pre-scale for next layer)

__global__ __launch_bounds__(256) void k_layer1(const float2* __restrict__ xs,
        const int* __restrict__ rowptr, const int* __restrict__ col,
        const float* __restrict__ dis, const float* __restrict__ W1,
        const float* __restrict__ b1, float* __restrict__ hout) {
    int tid = threadIdx.x, lane = tid & 63, wv = tid >> 6;
    int node = blockIdx.x * 4 + wv;
    if (node >= NN) return;
    int start = rowptr[node], end = rowptr[node + 1];
    float ax = 0.f, ay = 0.f;
    for (int base = start; base < end; base += 64) {
        int idx = base + lane;
        bool ok = idx < end;
        int s = ok ? col[idx] : 0;
        float2 xv = xs[s];
        if (ok) { ax += xv.x; ay += xv.y; }
    }
#pragma unroll
    for (int off = 32; off; off >>= 1) {
        ax += __shfl_xor(ax, off);
        ay += __shfl_xor(ay, off);
    }
    float dd = dis[node];
    ax *= dd; ay *= dd;
    float o = fmaxf(ax * W1[lane] + ay * W1[HD + lane] + b1[lane], 0.f);
    hout[node * HD + lane] = o * dd;
}

// layers 2/3: gather-aggregate 64-wide rows with 8 loads in flight, then
// transform by W[64,64]. LAST fuses the final @Wl + bl dot.
template <bool LAST>
__global__ __launch_bounds__(256) void k_layer(const float* __restrict__ hin,
        const int* __restrict__ rowptr, const int* __restrict__ col,
        const float* __restrict__ dis, const float* __restrict__ W,
        const float* __restrict__ b, const float* __restrict__ Wl,
        const float* __restrict__ bl, float* __restrict__ out) {
    int tid = threadIdx.x, lane = tid & 63, wv = tid >> 6;
    int node = blockIdx.x * 4 + wv;
    if (node >= NN) return;

    int start = rowptr[node], end = rowptr[node + 1];
    float agg = 0.f;
    for (int base = start; base < end; base += 64) {
        int colv = col[base + lane];          // coalesced; pad covers overread
        int m = min(64, end - base);
        for (int t = 0; t < m; t += 8) {
            // 8 independent row gathers in flight; out-of-range slots clamp to
            // the zeroed dummy row (single 256B line, stays cache-resident).
            int o0 = (t + 0 < m) ? __builtin_amdgcn_readlane(colv, (t + 0) & 63) * HD : DUMMY_OFF;
            int o1 = (t + 1 < m) ? __builtin_amdgcn_readlane(colv, (t + 1) & 63) * HD : DUMMY_OFF;
            int o2 = (t + 2 < m) ? __builtin_amdgcn_readlane(colv, (t + 2) & 63) * HD : DUMMY_OFF;
            int o3 = (t + 3 < m) ? __builtin_amdgcn_readlane(colv, (t + 3) & 63) * HD : DUMMY_OFF;
            int o4 = (t + 4 < m) ? __builtin_amdgcn_readlane(colv, (t + 4) & 63) * HD : DUMMY_OFF;
            int o5 = (t + 5 < m) ? __builtin_amdgcn_readlane(colv, (t + 5) & 63) * HD : DUMMY_OFF;
            int o6 = (t + 6 < m) ? __builtin_amdgcn_readlane(colv, (t + 6) & 63) * HD : DUMMY_OFF;
            int o7 = (t + 7 < m) ? __builtin_amdgcn_readlane(colv, (t + 7) & 63) * HD : DUMMY_OFF;
            float v0 = hin[o0 + lane];
            float v1 = hin[o1 + lane];
            float v2 = hin[o2 + lane];
            float v3 = hin[o3 + lane];
            float v4 = hin[o4 + lane];
            float v5 = hin[o5 + lane];
            float v6 = hin[o6 + lane];
            float v7 = hin[o7 + lane];
            agg += ((v0 + v1) + (v2 + v3)) + ((v4 + v5) + (v6 + v7));
        }
    }
    agg *= dis[node];

    // transform: o = relu(agg @ W + b), 4 accumulators to break the FMA chain
    float o0 = b[lane], o1 = 0.f, o2 = 0.f, o3 = 0.f;
#pragma unroll
    for (int k = 0; k < HD; k += 4) {
        float a0 = __int_as_float(__builtin_amdgcn_readlane(__float_as_int(agg), k + 0));
        float a1 = __int_as_float(__builtin_amdgcn_readlane(__float_as_int(agg), k + 1));
        float a2 = __int_as_float(__builtin_amdgcn_readlane(__float_as_int(agg), k + 2));
        float a3 = __int_as_float(__builtin_amdgcn_readlane(__float_as_int(agg), k + 3));
        o0 = fmaf(a0, W[(k + 0) * HD + lane], o0);
        o1 = fmaf(a1, W[(k + 1) * HD + lane], o1);
        o2 = fmaf(a2, W[(k + 2) * HD + lane], o2);
        o3 = fmaf(a3, W[(k + 3) * HD + lane], o3);
    }
    float o = fmaxf((o0 + o1) + (o2 + o3), 0.f);

    if (!LAST) {
        out[node * HD + lane] = o * dis[node];
    } else {
        float v = o * Wl[lane];
#pragma unroll
        for (int off = 32; off; off >>= 1) v += __shfl_xor(v, off);
        if (lane == 0) out[node] = v + bl[0];
    }
}

// ---------------- launch ----------------

extern "C" void kernel_launch(void* const* d_in, const int* in_sizes, int n_in,
                              void* d_out, int out_size, void* d_ws, size_t ws_size,
                              hipStream_t stream) {
    const float* x  = (const float*)d_in[0];
    const int*   ei = (const int*)d_in[1];   // [2,E]: src = ei[0:E], dst = ei[E:2E]
    const float* W1 = (const float*)d_in[2];
    const float* b1 = (const float*)d_in[3];
    const float* W2 = (const float*)d_in[4];
    const float* b2 = (const float*)d_in[5];
    const float* W3 = (const float*)d_in[6];
    const float* b3 = (const float*)d_in[7];
    const float* Wl = (const float*)d_in[8];
    const float* bl = (const float*)d_in[9];

    // workspace layout
    int*    cnt    = (int*)d_ws;                      // NN (reused as fill)
    float*  dis    = (float*)(cnt + NN);              // NN
    int*    rowptr = (int*)(dis + NN);                // NN+2
    int*    loc    = rowptr + (NN + 2);               // NN
    int*    boff   = loc + NN;                        // NCHUNK+2
    int*    col    = boff + (NCHUNK + 2);             // NN+NE+64 (overread pad)
    float2* xs     = (float2*)(col + (NN + NE + 64)); // NN
    float*  hA     = (float*)(xs + NN);               // (NN+1)*HD (dummy row)
    float*  hB     = hA + (size_t)(NN + 1) * HD;      // (NN+1)*HD

    const int B = 256;
    const int gN   = (NN + B - 1) / B;
    const int gE   = (NE + B - 1) / B;
    const int gRow = (NN + 3) / 4;

    // CSR + normalization
    k_init<<<gN, B, 0, stream>>>(cnt);
    k_count<<<gE, B, 0, stream>>>(ei + NE, cnt);
    k_scan1<<<NCHUNK, SCAN_B, 0, stream>>>(cnt, loc, rowptr /*bsum scratch? no*/);
    // NOTE: bsum needs its own storage; reuse boff+NCHUNK? keep separate below.
    k_scan2<<<1, 64, 0, stream>>>(rowptr /*bsum*/, boff);
    k_dis<<<gN, B, 0, stream>>>(cnt, dis);
    k_prep<<<gN, B, 0, stream>>>(loc, boff, rowptr, cnt /*fill*/, col,
                                 (const float2*)x, dis, xs, hA, hB);
    k_fill<<<gE, B, 0, stream>>>(ei, rowptr, cnt /*fill*/, col);

    // fused layers
    k_layer1<<<gRow, B, 0, stream>>>(xs, rowptr, col, dis, W1, b1, hA);
    k_layer<false><<<gRow, B, 0, stream>>>(hA, rowptr, col, dis, W2, b2, nullptr, nullptr, hB);
    k_layer<true ><<<gRow, B, 0, stream>>>(hB, rowptr, col, dis, W3, b3, Wl, bl, (float*)d_out);
}

// Round 4
// 249.889 us; speedup vs baseline: 3.9177x; 1.1268x over previous
//
#include <hip/hip_runtime.h>
#include <hip/hip_bf16.h>

#define NN 100000
#define NE 1000000
#define HD 64
#define SCAN_B 1024
#define NCHUNK ((NN + SCAN_B - 1) / SCAN_B)   // 98
#define DUMMYB (NN << 7)                      // dummy row byte offset (bf16 row = 128 B)

typedef unsigned short u16;
typedef unsigned int u32;

__device__ __forceinline__ u16 f2b(float f) {
    __hip_bfloat16 h = __float2bfloat16(f);   // RNE
    return *reinterpret_cast<u16*>(&h);
}
__device__ __forceinline__ float bload(const char* base, int byteoff, int lane) {
    u16 u = *(const u16*)(base + byteoff + 2 * lane);
    return __uint_as_float(((u32)u) << 16);
}

// ---------------- CSR build ----------------

__global__ void k_count(const int* __restrict__ dst, int* __restrict__ cnt) {
    int e = blockIdx.x * blockDim.x + threadIdx.x;
    if (e < NE) atomicAdd(&cnt[dst[e]], 1);
}

// per-block exclusive scan of padded counts pcnt_i = (cnt_i + 1 + 7) & ~7
__global__ __launch_bounds__(1024) void k_scan1(const int* __restrict__ cnt,
                                                int* __restrict__ loc,
                                                int* __restrict__ bsum) {
    __shared__ int wsum[16];
    int tid = threadIdx.x, lane = tid & 63, w = tid >> 6;
    int i = blockIdx.x * SCAN_B + tid;
    int v = (i < NN) ? ((cnt[i] + 8) & ~7) : 0;
    int s = v;
#pragma unroll
    for (int off = 1; off < 64; off <<= 1) { int t = __shfl_up(s, off); if (lane >= off) s += t; }
    if (lane == 63) wsum[w] = s;
    __syncthreads();
    if (tid < 16) {
        int ws = wsum[tid];
#pragma unroll
        for (int off = 1; off < 16; off <<= 1) { int t = __shfl_up(ws, off); if (tid >= off) ws += t; }
        wsum[tid] = ws;
    }
    __syncthreads();
    int prev = w ? wsum[w - 1] : 0;
    if (i < NN) loc[i] = prev + s - v;
    if (tid == SCAN_B - 1) bsum[blockIdx.x] = prev + s;
}

__global__ __launch_bounds__(64) void k_scan2(const int* __restrict__ bsum,
                                              int* __restrict__ boff) {
    int l = threadIdx.x;
    int a0 = (2 * l     < NCHUNK) ? bsum[2 * l]     : 0;
    int a1 = (2 * l + 1 < NCHUNK) ? bsum[2 * l + 1] : 0;
    int p = a0 + a1, s = p;
#pragma unroll
    for (int off = 1; off < 64; off <<= 1) { int t = __shfl_up(s, off); if (l >= off) s += t; }
    int ep = s - p;
    if (2 * l     < NCHUNK) boff[2 * l]     = ep;
    if (2 * l + 1 < NCHUNK) boff[2 * l + 1] = ep + a0;
}

// rowptr, dis, self-loop entry, pad entries, fill init, pre-scaled x, dummy rows.
// cntfill: read as cnt, re-init as fill counter (same buffer).
__global__ void k_prep(int* cntfill, const int* __restrict__ loc,
                       const int* __restrict__ boff, int* __restrict__ rowptr,
                       int* __restrict__ col, const float2* __restrict__ x2,
                       float* __restrict__ dis, float2* __restrict__ xs,
                       u16* __restrict__ hA, u16* __restrict__ hB) {
    int i = blockIdx.x * blockDim.x + threadIdx.x;
    if (i < HD) { hA[NN * HD + i] = 0; hB[NN * HD + i] = 0; }
    if (i == 0) xs[NN] = make_float2(0.f, 0.f);
    if (i >= NN) return;
    int c  = cntfill[i];
    int pc = (c + 8) & ~7;
    int r  = loc[i] + boff[i >> 10];
    rowptr[i] = r;
    if (i == NN - 1) rowptr[NN] = r + pc;
    float d = rsqrtf((float)(c + 1));
    dis[i] = d;
    cntfill[i] = 1;                 // slot 0 = self-loop
    col[r] = i << 7;
    for (int t = c + 1; t < pc; ++t) col[r + t] = DUMMYB;
    float2 xv = x2[i];
    xs[i] = make_float2(xv.x * d, xv.y * d);
}

__global__ void k_fill(const int* __restrict__ ei, const int* __restrict__ rowptr,
                       int* __restrict__ fill, int* __restrict__ col) {
    int e = blockIdx.x * blockDim.x + threadIdx.x;
    if (e >= NE) return;
    int d = ei[NE + e];
    int pos = rowptr[d] + atomicAdd(&fill[d], 1);
    col[pos] = ei[e] << 7;
}

// ---------------- fused layers ----------------
// invariant: stored rows pre-scaled by dis[src]; agg scaled by dis[d];
// non-last layers store bf16( relu(agg@W+b) * dis[node] )

__global__ __launch_bounds__(256) void k_layer1(const float2* __restrict__ xs,
        const int* __restrict__ rowptr, const int* __restrict__ col,
        const float* __restrict__ dis, const float* __restrict__ W1,
        const float* __restrict__ b1, u16* __restrict__ hout) {
    int tid = threadIdx.x, lane = tid & 63, wv = tid >> 6;
    int node = blockIdx.x * 4 + wv;
    if (node >= NN) return;
    int s = rowptr[node], e = rowptr[node + 1];
    float ax = 0.f, ay = 0.f;
    for (int base = s; base < e; base += 64) {
        int idx = base + lane;
        int cv = (idx < e) ? col[idx] : DUMMYB;           // pads/dummy add 0
        float2 xv = *(const float2*)((const char*)xs + (size_t)((u32)cv >> 4));
        ax += xv.x; ay += xv.y;
    }
#pragma unroll
    for (int off = 32; off; off >>= 1) { ax += __shfl_xor(ax, off); ay += __shfl_xor(ay, off); }
    float dd = dis[node];
    ax *= dd; ay *= dd;
    float o = fmaxf(fmaf(ax, W1[lane], fmaf(ay, W1[HD + lane], b1[lane])), 0.f);
    hout[node * HD + lane] = f2b(o * dd);
}

// layers 2/3: 4 nodes per wave. Gather: 8 bf16-row loads in flight, no selects
// (padded CSR). Transform: per k one W load shared by 4 fma.
template <bool LAST>
__global__ __launch_bounds__(256) void k_layer(const u16* __restrict__ hin,
        const int* __restrict__ rowptr, const int* __restrict__ col,
        const float* __restrict__ dis, const float* __restrict__ W,
        const float* __restrict__ b, const float* __restrict__ Wl,
        const float* __restrict__ bl, u16* __restrict__ hout,
        float* __restrict__ fout) {
    int tid = threadIdx.x, lane = tid & 63, wv = tid >> 6;
    int n0 = (blockIdx.x * 4 + wv) * 4;          // NN % 16 == 0: no tail
    const char* hb = (const char*)hin;

    float agg[4], dsv[4];
#pragma unroll
    for (int q = 0; q < 4; ++q) {
        int node = n0 + q;
        int s = rowptr[node], e = rowptr[node + 1];
        float a = 0.f;
        for (int base = s; base < e; base += 64) {
            int cv = col[base + lane];           // byte offsets, padded to x8
            int m = min(64, e - base);
            for (int t = 0; t < m; t += 8) {
                int o0 = __builtin_amdgcn_readlane(cv, t + 0);
                int o1 = __builtin_amdgcn_readlane(cv, t + 1);
                int o2 = __builtin_amdgcn_readlane(cv, t + 2);
                int o3 = __builtin_amdgcn_readlane(cv, t + 3);
                int o4 = __builtin_amdgcn_readlane(cv, t + 4);
                int o5 = __builtin_amdgcn_readlane(cv, t + 5);
                int o6 = __builtin_amdgcn_readlane(cv, t + 6);
                int o7 = __builtin_amdgcn_readlane(cv, t + 7);
                float v0 = bload(hb, o0, lane);
                float v1 = bload(hb, o1, lane);
                float v2 = bload(hb, o2, lane);
                float v3 = bload(hb, o3, lane);
                float v4 = bload(hb, o4, lane);
                float v5 = bload(hb, o5, lane);
                float v6 = bload(hb, o6, lane);
                float v7 = bload(hb, o7, lane);
                a += ((v0 + v1) + (v2 + v3)) + ((v4 + v5) + (v6 + v7));
            }
        }
        float dd = dis[node];
        dsv[q] = dd;
        agg[q] = a * dd;
    }

    float bb = b[lane];
    float o[4] = {bb, bb, bb, bb};
#pragma unroll
    for (int k = 0; k < HD; ++k) {
        float w = W[k * HD + lane];              // one load feeds 4 nodes
#pragma unroll
        for (int q = 0; q < 4; ++q) {
            float a = __int_as_float(__builtin_amdgcn_readlane(__float_as_int(agg[q]), k));
            o[q] = fmaf(a, w, o[q]);
        }
    }

    if (!LAST) {
#pragma unroll
        for (int q = 0; q < 4; ++q)
            hout[(n0 + q) * HD + lane] = f2b(fmaxf(o[q], 0.f) * dsv[q]);
    } else {
        float wl = Wl[lane];
        float r0, r1, r2, r3;
#pragma unroll
        for (int q = 0; q < 4; ++q) {
            float v = fmaxf(o[q], 0.f) * wl;
#pragma unroll
            for (int off = 32; off; off >>= 1) v += __shfl_xor(v, off);
            if (q == 0) r0 = v; else if (q == 1) r1 = v; else if (q == 2) r2 = v; else r3 = v;
        }
        float r = (lane == 0) ? r0 : (lane == 1) ? r1 : (lane == 2) ? r2 : r3;
        if (lane < 4) fout[n0 + lane] = r + bl[0];
    }
}

// ---------------- launch ----------------

extern "C" void kernel_launch(void* const* d_in, const int* in_sizes, int n_in,
                              void* d_out, int out_size, void* d_ws, size_t ws_size,
                              hipStream_t stream) {
    const float* x  = (const float*)d_in[0];
    const int*   ei = (const int*)d_in[1];   // [2,E]: src = ei[0:E], dst = ei[E:2E]
    const float* W1 = (const float*)d_in[2];
    const float* b1 = (const float*)d_in[3];
    const float* W2 = (const float*)d_in[4];
    const float* b2 = (const float*)d_in[5];
    const float* W3 = (const float*)d_in[6];
    const float* b3 = (const float*)d_in[7];
    const float* Wl = (const float*)d_in[8];
    const float* bl = (const float*)d_in[9];

    // workspace layout (int counts kept even -> 8B alignment everywhere)
    int*    cnt    = (int*)d_ws;                       // NN (reused as fill)
    float*  dis    = (float*)(cnt + NN);               // NN
    int*    rowptr = (int*)(dis + NN);                 // NN+1 (+1 pad); also bsum scratch
    int*    loc    = rowptr + (NN + 2);                // NN
    int*    boff   = loc + NN;                         // NCHUNK (pad to 128)
    int*    col    = boff + 128;                       // <= NE + 8*NN (+64 overread pad)
    float2* xs     = (float2*)(col + (NE + 8 * NN + 64)); // NN+1
    u16*    hA     = (u16*)(xs + (NN + 1));            // (NN+1)*HD bf16
    u16*    hB     = hA + (size_t)(NN + 1) * HD;       // (NN+1)*HD bf16

    const int B = 256;
    const int gN = (NN + B - 1) / B;
    const int gE = (NE + B - 1) / B;

    hipMemsetAsync(cnt, 0, NN * sizeof(int), stream);
    k_count<<<gE, B, 0, stream>>>(ei + NE, cnt);
    k_scan1<<<NCHUNK, SCAN_B, 0, stream>>>(cnt, loc, rowptr /*bsum scratch*/);
    k_scan2<<<1, 64, 0, stream>>>(rowptr /*bsum*/, boff);
    k_prep<<<gN, B, 0, stream>>>(cnt, loc, boff, rowptr, col,
                                 (const float2*)x, dis, xs, hA, hB);
    k_fill<<<gE, B, 0, stream>>>(ei, rowptr, cnt /*fill*/, col);

    k_layer1<<<(NN + 3) / 4, B, 0, stream>>>(xs, rowptr, col, dis, W1, b1, hA);
    k_layer<false><<<NN / 16, B, 0, stream>>>(hA, rowptr, col, dis, W2, b2,
                                              nullptr, nullptr, hB, nullptr);
    k_layer<true ><<<NN / 16, B, 0, stream>>>(hB, rowptr, col, dis, W3, b3,
                                              Wl, bl, nullptr, (float*)d_out);
}

// Round 5
// 191.600 us; speedup vs baseline: 5.1096x; 1.3042x over previous
//
#include <hip/hip_runtime.h>
#include <hip/hip_bf16.h>

#define NN 100000
#define NE 1000000
#define HD 64
#define NB 98                 // dst buckets of 1024 nodes
#define BSH 10
#define BCAP 12288            // bin capacity (avg 10240, +20 sigma)
#define EPB 8192              // edges per k_bin block
#define NB1 ((NE + EPB - 1) / EPB)   // 123
#define DUMMYB (NN << 7)      // dummy bf16 row byte offset

typedef unsigned short u16;
typedef unsigned int u32;
typedef unsigned long long u64;

__device__ __forceinline__ u16 f2b(float f) {
    __hip_bfloat16 h = __float2bfloat16(f);   // RNE
    return *reinterpret_cast<u16*>(&h);
}
__device__ __forceinline__ float bload(const char* base, int byteoff, int lane) {
    u16 u = *(const u16*)(base + byteoff + 2 * lane);
    return __uint_as_float(((u32)u) << 16);
}

// ---------------- CSR build: bucketed counting sort ----------------

// bin edges by dst>>10; per-block LDS histogram -> 98 reserve atomics -> coalesced append
__global__ __launch_bounds__(256) void k_bin(const int* __restrict__ ei,
                                             int* __restrict__ bfill,
                                             u64* __restrict__ bins) {
    __shared__ int hist[NB];
    __shared__ int base[NB];
    int tid = threadIdx.x;
    for (int i = tid; i < NB; i += 256) hist[i] = 0;
    __syncthreads();
    int e0 = blockIdx.x * EPB;
    int n = min(EPB, NE - e0);
    for (int i = tid; i < n; i += 256)
        atomicAdd(&hist[ei[NE + e0 + i] >> BSH], 1);
    __syncthreads();
    for (int i = tid; i < NB; i += 256) {
        int c = hist[i];
        base[i] = c ? atomicAdd(&bfill[i], c) : 0;
        hist[i] = 0;
    }
    __syncthreads();
    for (int i = tid; i < n; i += 256) {
        int s = ei[e0 + i];
        int d = ei[NE + e0 + i];
        int g = d >> BSH;
        int pos = base[g] + atomicAdd(&hist[g], 1);
        bins[(size_t)g * BCAP + min(pos, BCAP - 1)] = ((u64)(u32)d << 32) | (u32)s;
    }
}

// per-bucket padded row-length total
__global__ __launch_bounds__(256) void k_btot(const u64* __restrict__ bins,
                                              const int* __restrict__ bfill,
                                              int* __restrict__ btot) {
    __shared__ int cnt[1024];
    __shared__ int wtot[4];
    int g = blockIdx.x, tid = threadIdx.x;
    for (int i = tid; i < 1024; i += 256) cnt[i] = 0;
    __syncthreads();
    int n = min(bfill[g], BCAP);
    const u64* bp = bins + (size_t)g * BCAP;
    for (int i = tid; i < n; i += 256)
        atomicAdd(&cnt[(int)(bp[i] >> 32) & 1023], 1);
    __syncthreads();
    int part = 0;
    for (int i = tid; i < 1024; i += 256) {
        int node = (g << BSH) + i;
        if (node < NN) part += (cnt[i] + 8) & ~7;
    }
#pragma unroll
    for (int off = 32; off; off >>= 1) part += __shfl_xor(part, off);
    if ((tid & 63) == 0) wtot[tid >> 6] = part;
    __syncthreads();
    if (tid == 0) btot[g] = wtot[0] + wtot[1] + wtot[2] + wtot[3];
}

// per bucket: base, rowptr, self-loop+pads, dis, xs, and XCD-local edge scatter
__global__ __launch_bounds__(1024) void k_build(const u64* __restrict__ bins,
        const int* __restrict__ bfill, const int* __restrict__ btot,
        int* __restrict__ rowptr, int* __restrict__ col,
        const float2* __restrict__ x2, float* __restrict__ dis,
        float2* __restrict__ xs, u16* __restrict__ hA, u16* __restrict__ hB) {
    __shared__ int cnt[1024];
    __shared__ int rof[1024];
    __shared__ int wsum[16];
    __shared__ int gbase;
    int g = blockIdx.x, tid = threadIdx.x;
    int lane = tid & 63, w = tid >> 6;

    // bucket base = sum of btot[0..g-1] (block-wide reduce; NB=98 < 1024)
    int part = (tid < g) ? btot[tid] : 0;
#pragma unroll
    for (int off = 32; off; off >>= 1) part += __shfl_xor(part, off);
    if (lane == 0) wsum[w] = part;
    cnt[tid] = 0;
    __syncthreads();
    if (tid == 0) {
        int s = 0;
#pragma unroll
        for (int i = 0; i < 16; ++i) s += wsum[i];
        gbase = s;
        if (g == NB - 1) rowptr[NN] = s + btot[g];
    }
    __syncthreads();

    // histogram this bucket's edges
    int n = min(bfill[g], BCAP);
    const u64* bp = bins + (size_t)g * BCAP;
    for (int i = tid; i < n; i += 1024)
        atomicAdd(&cnt[(int)(bp[i] >> 32) & 1023], 1);
    __syncthreads();

    int node = (g << BSH) + tid;
    int c = cnt[tid];
    int pc = (node < NN) ? ((c + 8) & ~7) : 0;

    // block-wide exclusive scan of pc
    int s = pc;
#pragma unroll
    for (int off = 1; off < 64; off <<= 1) { int t = __shfl_up(s, off); if (lane >= off) s += t; }
    if (lane == 63) wsum[w] = s;
    __syncthreads();
    if (tid < 16) {
        int ws = wsum[tid];
#pragma unroll
        for (int off = 1; off < 16; off <<= 1) { int t = __shfl_up(ws, off); if (tid >= off) ws += t; }
        wsum[tid] = ws;
    }
    __syncthreads();
    int r = gbase + (w ? wsum[w - 1] : 0) + s - pc;
    rof[tid] = r;
    if (node < NN) {
        rowptr[node] = r;
        col[r] = node << 7;                               // self-loop slot 0
        for (int t = c + 1; t < pc; ++t) col[r + t] = DUMMYB;
        float dd = rsqrtf((float)(c + 1));
        dis[node] = dd;
        float2 xv = x2[node];
        xs[node] = make_float2(xv.x * dd, xv.y * dd);
    }
    cnt[tid] = 1;                                         // fill counter (slot 0 taken)
    __syncthreads();

    // scatter edges into this bucket's contiguous col region (single CU -> L2-local)
    for (int i = tid; i < n; i += 1024) {
        u64 e = bp[i];
        int d = (int)(e >> 32) & 1023;
        int src = (int)(e & 0xffffffffu);
        int local = atomicAdd(&cnt[d], 1);
        col[rof[d] + local] = src << 7;
    }

    if (g == 0) {
        if (tid < HD) { hA[NN * HD + tid] = 0; hB[NN * HD + tid] = 0; }
        if (tid == 0) xs[NN] = make_float2(0.f, 0.f);
    }
}

// ---------------- fused layers ----------------
// invariant: stored rows pre-scaled by dis[src]; agg scaled by dis[d];
// non-last layers store bf16( relu(agg@W+b) * dis[node] )

__global__ __launch_bounds__(256) void k_layer1(const float2* __restrict__ xs,
        const int* __restrict__ rowptr, const int* __restrict__ col,
        const float* __restrict__ dis, const float* __restrict__ W1,
        const float* __restrict__ b1, u16* __restrict__ hout) {
    int tid = threadIdx.x, lane = tid & 63, wv = tid >> 6;
    int node = blockIdx.x * 4 + wv;
    if (node >= NN) return;
    int s = rowptr[node], e = rowptr[node + 1];
    float ax = 0.f, ay = 0.f;
    for (int base = s; base < e; base += 64) {
        int idx = base + lane;
        int cv = (idx < e) ? col[idx] : DUMMYB;           // pads/dummy add 0
        float2 xv = *(const float2*)((const char*)xs + (size_t)((u32)cv >> 4));
        ax += xv.x; ay += xv.y;
    }
#pragma unroll
    for (int off = 32; off; off >>= 1) { ax += __shfl_xor(ax, off); ay += __shfl_xor(ay, off); }
    float dd = dis[node];
    ax *= dd; ay *= dd;
    float o = fmaxf(fmaf(ax, W1[lane], fmaf(ay, W1[HD + lane], b1[lane])), 0.f);
    hout[node * HD + lane] = f2b(o * dd);
}

// layers 2/3: 4 nodes per wave, 8 bf16-row gathers in flight, padded CSR (no selects)
template <bool LAST>
__global__ __launch_bounds__(256) void k_layer(const u16* __restrict__ hin,
        const int* __restrict__ rowptr, const int* __restrict__ col,
        const float* __restrict__ dis, const float* __restrict__ W,
        const float* __restrict__ b, const float* __restrict__ Wl,
        const float* __restrict__ bl, u16* __restrict__ hout,
        float* __restrict__ fout) {
    int tid = threadIdx.x, lane = tid & 63, wv = tid >> 6;
    int n0 = (blockIdx.x * 4 + wv) * 4;          // NN % 16 == 0: no tail
    const char* hb = (const char*)hin;

    float agg[4], dsv[4];
#pragma unroll
    for (int q = 0; q < 4; ++q) {
        int node = n0 + q;
        int s = rowptr[node], e = rowptr[node + 1];
        float a = 0.f;
        for (int base = s; base < e; base += 64) {
            int cv = col[base + lane];
            int m = min(64, e - base);
            for (int t = 0; t < m; t += 8) {
                int o0 = __builtin_amdgcn_readlane(cv, t + 0);
                int o1 = __builtin_amdgcn_readlane(cv, t + 1);
                int o2 = __builtin_amdgcn_readlane(cv, t + 2);
                int o3 = __builtin_amdgcn_readlane(cv, t + 3);
                int o4 = __builtin_amdgcn_readlane(cv, t + 4);
                int o5 = __builtin_amdgcn_readlane(cv, t + 5);
                int o6 = __builtin_amdgcn_readlane(cv, t + 6);
                int o7 = __builtin_amdgcn_readlane(cv, t + 7);
                float v0 = bload(hb, o0, lane);
                float v1 = bload(hb, o1, lane);
                float v2 = bload(hb, o2, lane);
                float v3 = bload(hb, o3, lane);
                float v4 = bload(hb, o4, lane);
                float v5 = bload(hb, o5, lane);
                float v6 = bload(hb, o6, lane);
                float v7 = bload(hb, o7, lane);
                a += ((v0 + v1) + (v2 + v3)) + ((v4 + v5) + (v6 + v7));
            }
        }
        float dd = dis[node];
        dsv[q] = dd;
        agg[q] = a * dd;
    }

    float bb = b[lane];
    float o[4] = {bb, bb, bb, bb};
#pragma unroll
    for (int k = 0; k < HD; ++k) {
        float w = W[k * HD + lane];              // one load feeds 4 nodes
#pragma unroll
        for (int q = 0; q < 4; ++q) {
            float a = __int_as_float(__builtin_amdgcn_readlane(__float_as_int(agg[q]), k));
            o[q] = fmaf(a, w, o[q]);
        }
    }

    if (!LAST) {
#pragma unroll
        for (int q = 0; q < 4; ++q)
            hout[(n0 + q) * HD + lane] = f2b(fmaxf(o[q], 0.f) * dsv[q]);
    } else {
        float wl = Wl[lane];
        float r0, r1, r2, r3;
#pragma unroll
        for (int q = 0; q < 4; ++q) {
            float v = fmaxf(o[q], 0.f) * wl;
#pragma unroll
            for (int off = 32; off; off >>= 1) v += __shfl_xor(v, off);
            if (q == 0) r0 = v; else if (q == 1) r1 = v; else if (q == 2) r2 = v; else r3 = v;
        }
        float r = (lane == 0) ? r0 : (lane == 1) ? r1 : (lane == 2) ? r2 : r3;
        if (lane < 4) fout[n0 + lane] = r + bl[0];
    }
}

// ---------------- launch ----------------

extern "C" void kernel_launch(void* const* d_in, const int* in_sizes, int n_in,
                              void* d_out, int out_size, void* d_ws, size_t ws_size,
                              hipStream_t stream) {
    const float* x  = (const float*)d_in[0];
    const int*   ei = (const int*)d_in[1];   // [2,E]: src = ei[0:E], dst = ei[E:2E]
    const float* W1 = (const float*)d_in[2];
    const float* b1 = (const float*)d_in[3];
    const float* W2 = (const float*)d_in[4];
    const float* b2 = (const float*)d_in[5];
    const float* W3 = (const float*)d_in[6];
    const float* b3 = (const float*)d_in[7];
    const float* Wl = (const float*)d_in[8];
    const float* bl = (const float*)d_in[9];

    // workspace layout (bins first: u64-aligned)
    u64*    bins   = (u64*)d_ws;                       // NB*BCAP u64   (9.6 MB)
    float2* xs     = (float2*)(bins + (size_t)NB * BCAP); // NN+1
    int*    bfill  = (int*)(xs + (NN + 1));            // NB (pad 128)
    int*    btot   = bfill + 128;                      // NB (pad 128)
    int*    rowptr = btot + 128;                       // NN+1 (+1 pad)
    float*  dis    = (float*)(rowptr + (NN + 2));      // NN
    int*    col    = (int*)(dis + NN);                 // NE + 8*NN + 64 overread pad
    u16*    hA     = (u16*)(col + (NE + 8 * NN + 64)); // (NN+1)*HD bf16
    u16*    hB     = hA + (size_t)(NN + 1) * HD;       // (NN+1)*HD bf16

    hipMemsetAsync(bfill, 0, NB * sizeof(int), stream);
    k_bin  <<<NB1, 256, 0, stream>>>(ei, bfill, bins);
    k_btot <<<NB, 256, 0, stream>>>(bins, bfill, btot);
    k_build<<<NB, 1024, 0, stream>>>(bins, bfill, btot, rowptr, col,
                                     (const float2*)x, dis, xs, hA, hB);

    k_layer1<<<(NN + 3) / 4, 256, 0, stream>>>(xs, rowptr, col, dis, W1, b1, hA);
    k_layer<false><<<NN / 16, 256, 0, stream>>>(hA, rowptr, col, dis, W2, b2,
                                                nullptr, nullptr, hB, nullptr);
    k_layer<true ><<<NN / 16, 256, 0, stream>>>(hB, rowptr, col, dis, W3, b3,
                                                Wl, bl, nullptr, (float*)d_out);
}